// Round 10
// baseline (62.961 us; speedup 1.0000x reference)
//
#include <hip/hip_runtime.h>

// ConcentrationLoss: pred,target [B=16,C=10,H=512,W=512] f32 -> scalar f32.
// R10 = R9 + partial-LLC pred split: target fully L3-resident (R9 result),
// plus the first 2/5 of each block's pred range loaded normally (L3-alloc,
// 64 MB grid-wide) and the rest nontemporal. Steady-state L3 = 168+64 =
// 232 MB < 256 MB; HBM serves only ~101 MB/replay.

#define HW 262144            // elements per slice
#define F4_SLICE 65536       // float4 per slice
#define SLICES 160
#define NBLK 2048            // one full residency round at 256 thr/block
#define V4B 5120             // float4 per block (NBLK*V4B == SLICES*F4_SLICE)
#define GROUPS 5             // V4B / 1024
#define CACHED_GROUPS 2      // pred groups 0,1 L3-allocating; 2-4 nontemporal
#define THREADS 256
#define NACC 8

typedef float vf4 __attribute__((ext_vector_type(4)));

__global__ __launch_bounds__(THREADS) void conc_pass1(
    const float* __restrict__ pred,
    const float* __restrict__ target,
    float* __restrict__ ws) {
  const int b = blockIdx.x;
  const int tid = threadIdx.x;
  const int start4 = b * V4B;
  const int lane = tid & 63, wave = tid >> 6;

  const vf4* __restrict__ p4 = reinterpret_cast<const vf4*>(pred);
  const vf4* __restrict__ t4 = reinterpret_cast<const vf4*>(target);

  // component accumulators (x-weighting deferred to flush epilogue)
  float T0 = 0.f, T1 = 0.f, T2 = 0.f, T3 = 0.f, Ty = 0.f;
  float G0 = 0.f, G1 = 0.f, G2 = 0.f, G3 = 0.f, Gy = 0.f, Gyy = 0.f;

  // thread-invariant column of this thread's float4 (.x element)
  const float x0c = (float)((tid & 127) << 2);

  __shared__ float red[4][NACC];

// Convert component sums -> canonical 8 moments, block-reduce, write record.
#define FLUSH(REC)                                                        \
  {                                                                       \
    const float x1c = x0c + 1.f, x2c = x0c + 2.f, x3c = x0c + 3.f;        \
    float acc[NACC];                                                      \
    acc[0] = (T0 + T1) + (T2 + T3);                                       \
    acc[1] = Ty;                                                          \
    acc[2] = (T0 * x0c + T1 * x1c) + (T2 * x2c + T3 * x3c);               \
    acc[3] = (G0 + G1) + (G2 + G3);                                       \
    acc[4] = Gy;                                                          \
    acc[5] = (G0 * x0c + G1 * x1c) + (G2 * x2c + G3 * x3c);               \
    acc[6] = Gyy;                                                         \
    acc[7] = (G0 * (x0c * x0c) + G1 * (x1c * x1c)) +                      \
             (G2 * (x2c * x2c) + G3 * (x3c * x3c));                       \
    _Pragma("unroll") for (int k = 0; k < NACC; ++k) {                    \
      float v = acc[k];                                                   \
      _Pragma("unroll") for (int off = 32; off > 0; off >>= 1)            \
          v += __shfl_down(v, off, 64);                                   \
      acc[k] = v;                                                         \
    }                                                                     \
    if (lane == 0) {                                                      \
      _Pragma("unroll") for (int k = 0; k < NACC; ++k)                    \
          red[wave][k] = acc[k];                                          \
    }                                                                     \
    __syncthreads();                                                      \
    if (tid < NACC)                                                       \
      ws[(size_t)(b * 2 + (REC)) * NACC + tid] =                          \
          red[0][tid] + red[1][tid] + red[2][tid] + red[3][tid];          \
    __syncthreads();                                                      \
    T0 = T1 = T2 = T3 = Ty = 0.f;                                        \
    G0 = G1 = G2 = G3 = Gy = Gyy = 0.f;                                   \
  }

  // group g (1024 float4 = 8 rows) lies entirely in one slice.
  const int off_in_slice = start4 & (F4_SLICE - 1);
  const bool crosses = (off_in_slice + V4B) > F4_SLICE;
  const int cg = crosses ? ((F4_SLICE - off_in_slice) >> 10) : GROUPS;

#pragma unroll
  for (int g = 0; g < GROUPS; ++g) {
    if (g == cg) FLUSH(0);  // block-uniform: entering the next slice
    const int g4 = start4 + g * 1024;
    // row of this thread's k=0 float4 within the slice
    const float yg = (float)(((g4 & (F4_SLICE - 1)) >> 7) + (tid >> 7));
    vf4 tb[4], pb[4];
#pragma unroll
    for (int k = 0; k < 4; ++k) {
      const int v4 = g4 + k * THREADS + tid;
      tb[k] = t4[v4];                 // target: always L3-resident
      if (g < CACHED_GROUPS)
        pb[k] = p4[v4];               // pred head: L3-allocating (64 MB total)
      else
        pb[k] = __builtin_nontemporal_load(p4 + v4);  // pred tail: stream
    }
#pragma unroll
    for (int k = 0; k < 4; ++k) {
      const float y = yg + (float)(2 * k);   // k advances 2 rows
      const vf4 t = tb[k];
      const vf4 p = pb[k];

      T0 += t.x; T1 += t.y; T2 += t.z; T3 += t.w;
      const float ts = (t.x + t.y) + (t.z + t.w);
      Ty += ts * y;

      const float g0 = 1.f / (1.f + __expf(-p.x));
      const float g1 = 1.f / (1.f + __expf(-p.y));
      const float g2 = 1.f / (1.f + __expf(-p.z));
      const float g3 = 1.f / (1.f + __expf(-p.w));
      G0 += g0; G1 += g1; G2 += g2; G3 += g3;
      const float gs = (g0 + g1) + (g2 + g3);
      const float gsy = gs * y;
      Gy  += gsy;
      Gyy += gsy * y;
    }
  }

  if (crosses) {
    FLUSH(1);
  } else {
    FLUSH(0);
    if (tid < NACC) ws[(size_t)(b * 2 + 1) * NACC + tid] = 0.f;  // empty rec 1
  }
#undef FLUSH
}

// thread t < 160 gathers all partials overlapping slice t (~13-14 records),
// finalizes in double, then one block reduction for the masked mean.
__global__ __launch_bounds__(THREADS) void conc_pass2(
    const float* __restrict__ ws, float* __restrict__ out) {
  const int tid = threadIdx.x;
  double lsum = 0.0;
  int nvalid = 0;

  if (tid < SLICES) {
    const int s = tid;
    float a[NACC];
#pragma unroll
    for (int k = 0; k < NACC; ++k) a[k] = 0.f;

    const int blo = (s * F4_SLICE) / V4B;
    const int bhi = ((s + 1) * F4_SLICE - 1) / V4B;  // inclusive
    for (int b = blo; b <= bhi; ++b) {
      const int first_slice = (b * V4B) >> 16;
      const int rec = (first_slice == s) ? 0 : 1;
      const float4* r =
          reinterpret_cast<const float4*>(ws + (size_t)(b * 2 + rec) * NACC);
      const float4 lo = r[0], hi = r[1];
      a[0] += lo.x; a[1] += lo.y; a[2] += lo.z; a[3] += lo.w;
      a[4] += hi.x; a[5] += hi.y; a[6] += hi.z; a[7] += hi.w;
    }

    const double tm = a[0], ty = a[1], tx = a[2];
    const double m0 = a[3], msy = a[4], msx = a[5], syy = a[6], sxx = a[7];
    const bool valid = tm > 0.0;
    const double mass = valid ? tm : 1.0;
    const double cy = ty / mass, cx = tx / mass;
    const double conc =
        syy + sxx - 2.0 * cy * msy - 2.0 * cx * msx + (cy * cy + cx * cx) * m0;
    if (valid) {
      lsum = conc / (double)HW;
      nvalid = 1;
    }
  }

  const int lane = tid & 63, wave = tid >> 6;
  double v = lsum;
  int n = nvalid;
#pragma unroll
  for (int off = 32; off > 0; off >>= 1) {
    v += __shfl_down(v, off, 64);
    n += __shfl_down(n, off, 64);
  }
  __shared__ double sd[4];
  __shared__ int si[4];
  if (lane == 0) { sd[wave] = v; si[wave] = n; }
  __syncthreads();
  if (tid == 0) {
    const double t = sd[0] + sd[1] + sd[2] + sd[3];
    const int nn = si[0] + si[1] + si[2] + si[3];
    out[0] = (float)((nn > 0) ? (t / (double)nn) : 0.0);
  }
}

extern "C" void kernel_launch(void* const* d_in, const int* in_sizes, int n_in,
                              void* d_out, int out_size, void* d_ws, size_t ws_size,
                              hipStream_t stream) {
  const float* pred = (const float*)d_in[0];
  const float* target = (const float*)d_in[1];
  float* ws = (float*)d_ws;   // needs NBLK*2*NACC*4 = 128 KiB
  float* out = (float*)d_out;

  conc_pass1<<<NBLK, THREADS, 0, stream>>>(pred, target, ws);
  conc_pass2<<<1, THREADS, 0, stream>>>(ws, out);
}

// Round 11
// 60.104 us; speedup vs baseline: 1.0475x; 1.0475x over previous
//
#include <hip/hip_runtime.h>

// ConcentrationLoss: pred,target [B=16,C=10,H=512,W=512] f32 -> scalar f32.
// R11 = R9 structure with ALL loads nontemporal. Ladder so far at constant
// FETCH (~164 MB): nt-fraction 0% -> 67.2us, 30% -> 63.0, 50% -> 60.4.

#define HW 262144            // elements per slice
#define F4_SLICE 65536       // float4 per slice
#define SLICES 160
#define NBLK 2048            // one full residency round at 256 thr/block
#define V4B 5120             // float4 per block (NBLK*V4B == SLICES*F4_SLICE)
#define GROUPS 5             // V4B / 1024
#define THREADS 256
#define NACC 8

typedef float vf4 __attribute__((ext_vector_type(4)));

__global__ __launch_bounds__(THREADS) void conc_pass1(
    const float* __restrict__ pred,
    const float* __restrict__ target,
    float* __restrict__ ws) {
  const int b = blockIdx.x;
  const int tid = threadIdx.x;
  const int start4 = b * V4B;
  const int lane = tid & 63, wave = tid >> 6;

  const vf4* __restrict__ p4 = reinterpret_cast<const vf4*>(pred);
  const vf4* __restrict__ t4 = reinterpret_cast<const vf4*>(target);

  // component accumulators (x-weighting deferred to flush epilogue)
  float T0 = 0.f, T1 = 0.f, T2 = 0.f, T3 = 0.f, Ty = 0.f;
  float G0 = 0.f, G1 = 0.f, G2 = 0.f, G3 = 0.f, Gy = 0.f, Gyy = 0.f;

  // thread-invariant column of this thread's float4 (.x element)
  const float x0c = (float)((tid & 127) << 2);

  __shared__ float red[4][NACC];

// Convert component sums -> canonical 8 moments, block-reduce, write record.
#define FLUSH(REC)                                                        \
  {                                                                       \
    const float x1c = x0c + 1.f, x2c = x0c + 2.f, x3c = x0c + 3.f;        \
    float acc[NACC];                                                      \
    acc[0] = (T0 + T1) + (T2 + T3);                                       \
    acc[1] = Ty;                                                          \
    acc[2] = (T0 * x0c + T1 * x1c) + (T2 * x2c + T3 * x3c);               \
    acc[3] = (G0 + G1) + (G2 + G3);                                       \
    acc[4] = Gy;                                                          \
    acc[5] = (G0 * x0c + G1 * x1c) + (G2 * x2c + G3 * x3c);               \
    acc[6] = Gyy;                                                         \
    acc[7] = (G0 * (x0c * x0c) + G1 * (x1c * x1c)) +                      \
             (G2 * (x2c * x2c) + G3 * (x3c * x3c));                       \
    _Pragma("unroll") for (int k = 0; k < NACC; ++k) {                    \
      float v = acc[k];                                                   \
      _Pragma("unroll") for (int off = 32; off > 0; off >>= 1)            \
          v += __shfl_down(v, off, 64);                                   \
      acc[k] = v;                                                         \
    }                                                                     \
    if (lane == 0) {                                                      \
      _Pragma("unroll") for (int k = 0; k < NACC; ++k)                    \
          red[wave][k] = acc[k];                                          \
    }                                                                     \
    __syncthreads();                                                      \
    if (tid < NACC)                                                       \
      ws[(size_t)(b * 2 + (REC)) * NACC + tid] =                          \
          red[0][tid] + red[1][tid] + red[2][tid] + red[3][tid];          \
    __syncthreads();                                                      \
    T0 = T1 = T2 = T3 = Ty = 0.f;                                         \
    G0 = G1 = G2 = G3 = Gy = Gyy = 0.f;                                   \
  }

  // group g (1024 float4 = 8 rows) lies entirely in one slice.
  const int off_in_slice = start4 & (F4_SLICE - 1);
  const bool crosses = (off_in_slice + V4B) > F4_SLICE;
  const int cg = crosses ? ((F4_SLICE - off_in_slice) >> 10) : GROUPS;

  for (int g = 0; g < GROUPS; ++g) {
    if (g == cg) FLUSH(0);  // block-uniform: entering the next slice
    const int g4 = start4 + g * 1024;
    // row of this thread's k=0 float4 within the slice
    const float yg = (float)(((g4 & (F4_SLICE - 1)) >> 7) + (tid >> 7));
    vf4 tb[4], pb[4];
#pragma unroll
    for (int k = 0; k < 4; ++k) {
      const int v4 = g4 + k * THREADS + tid;
      tb[k] = __builtin_nontemporal_load(t4 + v4);
      pb[k] = __builtin_nontemporal_load(p4 + v4);
    }
#pragma unroll
    for (int k = 0; k < 4; ++k) {
      const float y = yg + (float)(2 * k);   // k advances 2 rows
      const vf4 t = tb[k];
      const vf4 p = pb[k];

      T0 += t.x; T1 += t.y; T2 += t.z; T3 += t.w;
      const float ts = (t.x + t.y) + (t.z + t.w);
      Ty += ts * y;

      const float g0 = 1.f / (1.f + __expf(-p.x));
      const float g1 = 1.f / (1.f + __expf(-p.y));
      const float g2 = 1.f / (1.f + __expf(-p.z));
      const float g3 = 1.f / (1.f + __expf(-p.w));
      G0 += g0; G1 += g1; G2 += g2; G3 += g3;
      const float gs = (g0 + g1) + (g2 + g3);
      const float gsy = gs * y;
      Gy  += gsy;
      Gyy += gsy * y;
    }
  }

  if (crosses) {
    FLUSH(1);
  } else {
    FLUSH(0);
    if (tid < NACC) ws[(size_t)(b * 2 + 1) * NACC + tid] = 0.f;  // empty rec 1
  }
#undef FLUSH
}

// thread t < 160 gathers all partials overlapping slice t (~13-14 records),
// finalizes in double, then one block reduction for the masked mean.
__global__ __launch_bounds__(THREADS) void conc_pass2(
    const float* __restrict__ ws, float* __restrict__ out) {
  const int tid = threadIdx.x;
  double lsum = 0.0;
  int nvalid = 0;

  if (tid < SLICES) {
    const int s = tid;
    float a[NACC];
#pragma unroll
    for (int k = 0; k < NACC; ++k) a[k] = 0.f;

    const int blo = (s * F4_SLICE) / V4B;
    const int bhi = ((s + 1) * F4_SLICE - 1) / V4B;  // inclusive
    for (int b = blo; b <= bhi; ++b) {
      const int first_slice = (b * V4B) >> 16;
      const int rec = (first_slice == s) ? 0 : 1;
      const float4* r =
          reinterpret_cast<const float4*>(ws + (size_t)(b * 2 + rec) * NACC);
      const float4 lo = r[0], hi = r[1];
      a[0] += lo.x; a[1] += lo.y; a[2] += lo.z; a[3] += lo.w;
      a[4] += hi.x; a[5] += hi.y; a[6] += hi.z; a[7] += hi.w;
    }

    const double tm = a[0], ty = a[1], tx = a[2];
    const double m0 = a[3], msy = a[4], msx = a[5], syy = a[6], sxx = a[7];
    const bool valid = tm > 0.0;
    const double mass = valid ? tm : 1.0;
    const double cy = ty / mass, cx = tx / mass;
    const double conc =
        syy + sxx - 2.0 * cy * msy - 2.0 * cx * msx + (cy * cy + cx * cx) * m0;
    if (valid) {
      lsum = conc / (double)HW;
      nvalid = 1;
    }
  }

  const int lane = tid & 63, wave = tid >> 6;
  double v = lsum;
  int n = nvalid;
#pragma unroll
  for (int off = 32; off > 0; off >>= 1) {
    v += __shfl_down(v, off, 64);
    n += __shfl_down(n, off, 64);
  }
  __shared__ double sd[4];
  __shared__ int si[4];
  if (lane == 0) { sd[wave] = v; si[wave] = n; }
  __syncthreads();
  if (tid == 0) {
    const double t = sd[0] + sd[1] + sd[2] + sd[3];
    const int nn = si[0] + si[1] + si[2] + si[3];
    out[0] = (float)((nn > 0) ? (t / (double)nn) : 0.0);
  }
}

extern "C" void kernel_launch(void* const* d_in, const int* in_sizes, int n_in,
                              void* d_out, int out_size, void* d_ws, size_t ws_size,
                              hipStream_t stream) {
  const float* pred = (const float*)d_in[0];
  const float* target = (const float*)d_in[1];
  float* ws = (float*)d_ws;   // needs NBLK*2*NACC*4 = 128 KiB
  float* out = (float*)d_out;

  conc_pass1<<<NBLK, THREADS, 0, stream>>>(pred, target, ws);
  conc_pass2<<<1, THREADS, 0, stream>>>(ws, out);
}